// Round 7
// baseline (542.306 us; speedup 1.0000x reference)
//
#include <hip/hip_runtime.h>
#include <math.h>

#define E 100
#define NV 5000
#define NPART 64
#define CAP 16

// ws layout:
//   count:   int  [4][NV]            = 20,000 ints   (80 KB)
//   bucket:  int  [4][NV][CAP]       = 320,000 ints  (1.28 MB)
//   A:       float[4][NV][E]         = 2,000,000 f   (8 MB)  dense x-vectors
//   partial: float[NPART][2][E]      = 12,800 f      (51 KB)
//   hbuf:    float[300]
// total ~9.4 MB

__global__ void init_kernel(int* __restrict__ count, float* __restrict__ partial) {
    int p = blockIdx.x * blockDim.x + threadIdx.x;
    if (p < 4 * NV) count[p] = 0;
    if (p < NPART * 2 * E) partial[p] = 0.f;
}

// 40000 (cube,sent,edge) entries -> bucket lists per (cube,sent,verb).
__global__ void bucket_build_kernel(const int* __restrict__ vs1, const int* __restrict__ vo1,
                                    const int* __restrict__ vt1,
                                    const int* __restrict__ vs2, const int* __restrict__ vo2,
                                    const int* __restrict__ vt2,
                                    int* __restrict__ count, int* __restrict__ bucket) {
    int p = blockIdx.x * blockDim.x + threadIdx.x;
    if (p >= 40000) return;
    int sent = p / 20000;
    int r = p - sent * 20000;
    int kind = r / 5000;
    int idx = r - kind * 5000;
    const int* vs = sent ? vs2 : vs1;
    const int* vo = sent ? vo2 : vo1;
    const int* vt = sent ? vt2 : vt1;
    int verb, arg, cube;
    if (kind == 0)      { verb = vs[idx * 2]; arg = vs[idx * 2 + 1]; cube = 0; }
    else if (kind == 1) { verb = vo[idx * 2]; arg = vo[idx * 2 + 1]; cube = 1; }
    else if (kind == 2) { verb = vt[idx * 3]; arg = vt[idx * 3 + 1]; cube = 0; }
    else                { verb = vt[idx * 3]; arg = vt[idx * 3 + 2]; cube = 1; }
    int slot = (cube * 2 + sent) * NV + verb;
    int pos = atomicAdd(&count[slot], 1);
    if (pos < CAP) bucket[slot * CAP + pos] = arg;
}

// Dense x-vectors: thread per (slot, float4-chunk). 25 consecutive threads share a
// slot (bucket line L1-broadcast); gathers of ne4[id*25+c] are coalesced across c.
__global__ void build_A_kernel(const int* __restrict__ count, const int* __restrict__ bucket,
                               const float* __restrict__ noun_emb, float* __restrict__ A) {
    int p = blockIdx.x * blockDim.x + threadIdx.x;
    if (p >= 4 * NV * 25) return;
    int slot = p / 25, c = p - (p / 25) * 25;
    int n = count[slot]; if (n > CAP) n = CAP;
    const int4* b4 = (const int4*)(bucket + slot * CAP);
    int4 q0 = b4[0], q1 = b4[1], q2 = b4[2], q3 = b4[3];
    int ids[16] = {q0.x,q0.y,q0.z,q0.w, q1.x,q1.y,q1.z,q1.w,
                   q2.x,q2.y,q2.z,q2.w, q3.x,q3.y,q3.z,q3.w};
    const float4* ne4 = (const float4*)noun_emb;
    float ax = 0.f, ay = 0.f, az = 0.f, aw = 0.f;
    #pragma unroll
    for (int j = 0; j < CAP; j++)
        if (j < n) {
            float4 v = ne4[ids[j] * 25 + c];
            ax += v.x; ay += v.y; az += v.z; aw += v.w;
        }
    ((float4*)A)[p] = make_float4(ax, ay, az, aw);
}

// Word-embedding sums (unchanged; passed round 6).
__global__ __launch_bounds__(512) void word_sum_kernel(const int* __restrict__ w1,
                                                       const int* __restrict__ w2,
                                                       const float* __restrict__ noun_emb,
                                                       float* __restrict__ partial) {
    __shared__ int wid[400];
    __shared__ float wred[E];
    int b = blockIdx.x;            // 0..249
    int sent = b / 125;
    int cb = b - sent * 125;
    const int* words = sent ? w2 : w1;
    int t = threadIdx.x;
    if (t < 400) wid[t] = words[cb * 400 + t];
    if (t >= 400 && t < 500) wred[t - 400] = 0.f;
    __syncthreads();
    if (t < 500) {
        int wl = t / 25, k = t - (t / 25) * 25;
        const float4* ne4 = (const float4*)noun_emb;
        float ax = 0.f, ay = 0.f, az = 0.f, aw = 0.f;
        #pragma unroll
        for (int j = 0; j < 20; j++) {
            float4 v = ne4[wid[wl * 20 + j] * 25 + k];
            ax += v.x; ay += v.y; az += v.z; aw += v.w;
        }
        atomicAdd(&wred[k * 4 + 0], ax);
        atomicAdd(&wred[k * 4 + 1], ay);
        atomicAdd(&wred[k * 4 + 2], az);
        atomicAdd(&wred[k * 4 + 3], aw);
    }
    __syncthreads();
    if (t < 100) atomicAdd(&partial[((b & (NPART - 1)) * 2 + sent) * E + t], wred[t]);
}

// m13-style barrier-free cube stream. One thread per output row r (1,000,000 rows):
// cube = r/500000, v = (r%500000)/100, i = r%100. 25 fully-unrolled independent
// row loads (4 chunks per 64B line -> L1 reuse); x from dense A (L1/L2-hot,
// shared across the ~100 threads with the same v). No LDS, no syncthreads, no
// dependent preamble. 2 global atomics per thread, sliced over NPART copies.
__global__ __launch_bounds__(256, 4) void cube_stream_kernel(const float* __restrict__ subj,
                                                             const float* __restrict__ obj,
                                                             const float* __restrict__ A,
                                                             float* __restrict__ partial) {
    int r = blockIdx.x * 256 + threadIdx.x;
    if (r >= 2 * NV * E) return;
    int cube = r / (NV * E);
    int rem = r - cube * (NV * E);
    int v = rem / E, i = rem - v * E;
    const float4* row = (const float4*)(cube ? obj : subj) + (size_t)rem * 25;
    const float4* x1  = (const float4*)A + ((size_t)(cube * 2 + 0) * NV + v) * 25;
    const float4* x2  = (const float4*)A + ((size_t)(cube * 2 + 1) * NV + v) * 25;

    float a1e = 0.f, a1o = 0.f, a2e = 0.f, a2o = 0.f;
    #pragma unroll
    for (int k = 0; k < 24; k += 2) {
        float4 m0 = row[k],   m1 = row[k + 1];
        float4 p0 = x1[k],    p1 = x1[k + 1];
        float4 q0 = x2[k],    q1 = x2[k + 1];
        a1e += m0.x * p0.x + m0.y * p0.y + m0.z * p0.z + m0.w * p0.w;
        a1o += m1.x * p1.x + m1.y * p1.y + m1.z * p1.z + m1.w * p1.w;
        a2e += m0.x * q0.x + m0.y * q0.y + m0.z * q0.z + m0.w * q0.w;
        a2o += m1.x * q1.x + m1.y * q1.y + m1.z * q1.z + m1.w * q1.w;
    }
    {
        float4 m0 = row[24];
        float4 p0 = x1[24], q0 = x2[24];
        a1e += m0.x * p0.x + m0.y * p0.y + m0.z * p0.z + m0.w * p0.w;
        a2e += m0.x * q0.x + m0.y * q0.y + m0.z * q0.z + m0.w * q0.w;
    }
    int sl = (blockIdx.x & (NPART - 1)) * 2;
    atomicAdd(&partial[(sl + 0) * E + i], a1e + a1o);
    atomicAdd(&partial[(sl + 1) * E + i], a2e + a2o);
}

// Hidden GEMV with vd-reduction fused in (unchanged; passed round 6).
__global__ __launch_bounds__(512) void hidden_kernel(const float* __restrict__ partial,
                                                     const float* __restrict__ W_h,
                                                     const float* __restrict__ b_h,
                                                     float* __restrict__ hbuf) {
    __shared__ float vds[4 * E];
    int t = threadIdx.x;
    if (t < 200) {
        int s = t / 100, i = t - (t / 100) * 100;
        float sum = 0.f;
        #pragma unroll 8
        for (int p = 0; p < NPART; p++) sum += partial[(p * 2 + s) * E + i];
        vds[s * E + i] = sum;
    }
    __syncthreads();
    if (t < E) {
        float e1 = vds[t], e2 = vds[E + t];
        vds[2 * E + t] = e1 * e2;
        vds[3 * E + t] = fabsf(e1 - e2);
    }
    __syncthreads();
    int wave = t >> 6, lane = t & 63;
    int h = blockIdx.x * 8 + wave;
    if (h < 300) {
        const float4* w4 = (const float4*)(W_h + (size_t)h * 4 * E);
        const float4* v4 = (const float4*)vds;
        float4 w = w4[lane], v = v4[lane];
        float acc = w.x * v.x + w.y * v.y + w.z * v.z + w.w * v.w;
        if (lane < 36) {
            float4 w2 = w4[lane + 64], v2 = v4[lane + 64];
            acc += w2.x * v2.x + w2.y * v2.y + w2.z * v2.z + w2.w * v2.w;
        }
        #pragma unroll
        for (int off = 32; off > 0; off >>= 1) acc += __shfl_down(acc, off);
        if (lane == 0) hbuf[h] = 1.f / (1.f + expf(-(acc + b_h[h])));
    }
}

// Output layer + log_softmax. 512 threads (>=300 so hs is fully covered).
__global__ __launch_bounds__(512) void out_kernel(const float* __restrict__ hbuf,
                                                  const float* __restrict__ W_o,
                                                  const float* __restrict__ b_o,
                                                  float* __restrict__ out) {
    __shared__ float hs[300];
    __shared__ float o[3];
    int t = threadIdx.x;
    if (t < 300) hs[t] = hbuf[t];
    __syncthreads();
    int wave = t >> 6, lane = t & 63;
    if (wave < 3) {
        float acc = 0.f;
        #pragma unroll
        for (int j = 0; j < 5; j++) {
            int h = lane + j * 64;
            if (h < 300) acc += W_o[wave * 300 + h] * hs[h];
        }
        #pragma unroll
        for (int off = 32; off > 0; off >>= 1) acc += __shfl_down(acc, off);
        if (lane == 0) o[wave] = acc + b_o[wave];
    }
    __syncthreads();
    if (t == 0) {
        float m = fmaxf(o[0], fmaxf(o[1], o[2]));
        float l = logf(expf(o[0] - m) + expf(o[1] - m) + expf(o[2] - m)) + m;
        out[0] = o[0] - l;
        out[1] = o[1] - l;
        out[2] = o[2] - l;
    }
}

extern "C" void kernel_launch(void* const* d_in, const int* in_sizes, int n_in,
                              void* d_out, int out_size, void* d_ws, size_t ws_size,
                              hipStream_t stream) {
    const int* words1 = (const int*)d_in[0];
    const int* vs1    = (const int*)d_in[1];
    const int* vo1    = (const int*)d_in[2];
    const int* vt1    = (const int*)d_in[3];
    const int* words2 = (const int*)d_in[4];
    const int* vs2    = (const int*)d_in[5];
    const int* vo2    = (const int*)d_in[6];
    const int* vt2    = (const int*)d_in[7];
    const float* noun_emb = (const float*)d_in[8];
    const float* subj     = (const float*)d_in[9];
    const float* obj      = (const float*)d_in[10];
    const float* W_h      = (const float*)d_in[11];
    const float* b_h      = (const float*)d_in[12];
    const float* W_o      = (const float*)d_in[13];
    const float* b_o      = (const float*)d_in[14];
    float* out = (float*)d_out;

    int*   count   = (int*)d_ws;                      // 20,000 ints
    int*   bucket  = count + 4 * NV;                  // 320,000 ints
    float* A       = (float*)(bucket + 4 * NV * CAP); // 2,000,000 floats
    float* partial = A + 4 * NV * E;                  // 12,800 floats
    float* hbuf    = partial + NPART * 2 * E;         // 300 floats

    init_kernel<<<(4 * NV + 255) / 256, 256, 0, stream>>>(count, partial);
    bucket_build_kernel<<<(40000 + 255) / 256, 256, 0, stream>>>(
        vs1, vo1, vt1, vs2, vo2, vt2, count, bucket);
    build_A_kernel<<<(4 * NV * 25 + 255) / 256, 256, 0, stream>>>(count, bucket, noun_emb, A);
    word_sum_kernel<<<250, 512, 0, stream>>>(words1, words2, noun_emb, partial);
    cube_stream_kernel<<<(2 * NV * E + 255) / 256, 256, 0, stream>>>(subj, obj, A, partial);
    hidden_kernel<<<38, 512, 0, stream>>>(partial, W_h, b_h, hbuf);
    out_kernel<<<1, 512, 0, stream>>>(hbuf, W_o, b_o, out);
}

// Round 8
// 458.626 us; speedup vs baseline: 1.1825x; 1.1825x over previous
//
#include <hip/hip_runtime.h>
#include <math.h>

#define E 100
#define NV 5000
#define NPART 64
#define CAP 16

// ws layout:
//   count:   int  [4][NV]            = 20,000 ints
//   bucket:  int  [4][NV][CAP]       = 320,000 ints
//   A:       float[4][NV][E]         = 2,000,000 f   (8 MB) dense x-vectors
//   partial: float[NPART][2][E]      = 12,800 f
//   hbuf:    float[300]

__global__ void init_kernel(int* __restrict__ count, float* __restrict__ partial) {
    int p = blockIdx.x * blockDim.x + threadIdx.x;
    if (p < 4 * NV) count[p] = 0;
    if (p < NPART * 2 * E) partial[p] = 0.f;
}

__global__ void bucket_build_kernel(const int* __restrict__ vs1, const int* __restrict__ vo1,
                                    const int* __restrict__ vt1,
                                    const int* __restrict__ vs2, const int* __restrict__ vo2,
                                    const int* __restrict__ vt2,
                                    int* __restrict__ count, int* __restrict__ bucket) {
    int p = blockIdx.x * blockDim.x + threadIdx.x;
    if (p >= 40000) return;
    int sent = p / 20000;
    int r = p - sent * 20000;
    int kind = r / 5000;
    int idx = r - kind * 5000;
    const int* vs = sent ? vs2 : vs1;
    const int* vo = sent ? vo2 : vo1;
    const int* vt = sent ? vt2 : vt1;
    int verb, arg, cube;
    if (kind == 0)      { verb = vs[idx * 2]; arg = vs[idx * 2 + 1]; cube = 0; }
    else if (kind == 1) { verb = vo[idx * 2]; arg = vo[idx * 2 + 1]; cube = 1; }
    else if (kind == 2) { verb = vt[idx * 3]; arg = vt[idx * 3 + 1]; cube = 0; }
    else                { verb = vt[idx * 3]; arg = vt[idx * 3 + 2]; cube = 1; }
    int slot = (cube * 2 + sent) * NV + verb;
    int pos = atomicAdd(&count[slot], 1);
    if (pos < CAP) bucket[slot * CAP + pos] = arg;
}

// Dense x-vectors (unchanged; cheap — never appeared in top-5).
__global__ void build_A_kernel(const int* __restrict__ count, const int* __restrict__ bucket,
                               const float* __restrict__ noun_emb, float* __restrict__ A) {
    int p = blockIdx.x * blockDim.x + threadIdx.x;
    if (p >= 4 * NV * 25) return;
    int slot = p / 25, c = p - (p / 25) * 25;
    int n = count[slot]; if (n > CAP) n = CAP;
    const int4* b4 = (const int4*)(bucket + slot * CAP);
    int4 q0 = b4[0], q1 = b4[1], q2 = b4[2], q3 = b4[3];
    int ids[16] = {q0.x,q0.y,q0.z,q0.w, q1.x,q1.y,q1.z,q1.w,
                   q2.x,q2.y,q2.z,q2.w, q3.x,q3.y,q3.z,q3.w};
    const float4* ne4 = (const float4*)noun_emb;
    float ax = 0.f, ay = 0.f, az = 0.f, aw = 0.f;
    #pragma unroll
    for (int j = 0; j < CAP; j++)
        if (j < n) {
            float4 v = ne4[ids[j] * 25 + c];
            ax += v.x; ay += v.y; az += v.z; aw += v.w;
        }
    ((float4*)A)[p] = make_float4(ax, ay, az, aw);
}

// Word-embedding sums (unchanged; passed).
__global__ __launch_bounds__(512) void word_sum_kernel(const int* __restrict__ w1,
                                                       const int* __restrict__ w2,
                                                       const float* __restrict__ noun_emb,
                                                       float* __restrict__ partial) {
    __shared__ int wid[400];
    __shared__ float wred[E];
    int b = blockIdx.x;
    int sent = b / 125;
    int cb = b - sent * 125;
    const int* words = sent ? w2 : w1;
    int t = threadIdx.x;
    if (t < 400) wid[t] = words[cb * 400 + t];
    if (t >= 400 && t < 500) wred[t - 400] = 0.f;
    __syncthreads();
    if (t < 500) {
        int wl = t / 25, k = t - (t / 25) * 25;
        const float4* ne4 = (const float4*)noun_emb;
        float ax = 0.f, ay = 0.f, az = 0.f, aw = 0.f;
        #pragma unroll
        for (int j = 0; j < 20; j++) {
            float4 v = ne4[wid[wl * 20 + j] * 25 + k];
            ax += v.x; ay += v.y; az += v.z; aw += v.w;
        }
        atomicAdd(&wred[k * 4 + 0], ax);
        atomicAdd(&wred[k * 4 + 1], ay);
        atomicAdd(&wred[k * 4 + 2], az);
        atomicAdd(&wred[k * 4 + 3], aw);
    }
    __syncthreads();
    if (t < 100) atomicAdd(&partial[((b & (NPART - 1)) * 2 + sent) * E + t], wred[t]);
}

// One block per (cube, verb) panel. 500 threads sweep the 2500-float4 panel in 5
// strided passes: float4 index p = it*500 + t  ->  byte addr = base + 16*p, EXACT
// unit stride across the block (m13 pattern). The 5 loads/thread are independent
// (private acc[it]); x read once from LDS at fixed c = t%25. Reduction is plain
// LDS stores [2][100][25] (conflict-free), one barrier, 25-read sums, 200 global
// atomics. No LDS atomics, no waits inside the load loop.
__global__ __launch_bounds__(512, 6) void verb_panel_kernel(const float* __restrict__ subj,
                                                            const float* __restrict__ obj,
                                                            const float* __restrict__ A,
                                                            float* __restrict__ partial) {
    __shared__ float4 xs[2][25];      // x-vectors for this (cube,verb), both sentences
    __shared__ float  pl[2][E][25];   // per-thread partials: [sent][row][chunk] (20 KB)

    int b = blockIdx.x;               // b = cube*NV + v
    int cube = b / NV;
    int v = b - cube * NV;
    int t = threadIdx.x;

    if (t < 50) {
        int s = t / 25, c = t - (t / 25) * 25;
        xs[s][c] = ((const float4*)A)[((size_t)(cube * 2 + s) * NV + v) * 25 + c];
    }
    __syncthreads();

    if (t < 500) {
        int c = t % 25, r0 = t / 25;            // chunk 0..24, base row 0..19
        float4 x1 = xs[0][c], x2 = xs[1][c];
        const float4* panel = (const float4*)(cube ? obj : subj) + (size_t)v * 2500;
        float a1[5], a2[5];
        #pragma unroll
        for (int it = 0; it < 5; it++) {
            float4 m = panel[it * 500 + t];     // unit-stride across block
            a1[it] = m.x * x1.x + m.y * x1.y + m.z * x1.z + m.w * x1.w;
            a2[it] = m.x * x2.x + m.y * x2.y + m.z * x2.z + m.w * x2.w;
        }
        #pragma unroll
        for (int it = 0; it < 5; it++) {
            int row = it * 20 + r0;
            pl[0][row][c] = a1[it];
            pl[1][row][c] = a2[it];
        }
    }
    __syncthreads();

    if (t < 200) {
        int s = t / 100, row = t - (t / 100) * 100;
        float sum = 0.f;
        #pragma unroll
        for (int c = 0; c < 25; c++) sum += pl[s][row][c];
        atomicAdd(&partial[((b & (NPART - 1)) * 2 + s) * E + row], sum);
    }
}

// Hidden GEMV with vd-reduction fused in (unchanged; passed).
__global__ __launch_bounds__(512) void hidden_kernel(const float* __restrict__ partial,
                                                     const float* __restrict__ W_h,
                                                     const float* __restrict__ b_h,
                                                     float* __restrict__ hbuf) {
    __shared__ float vds[4 * E];
    int t = threadIdx.x;
    if (t < 200) {
        int s = t / 100, i = t - (t / 100) * 100;
        float sum = 0.f;
        #pragma unroll 8
        for (int p = 0; p < NPART; p++) sum += partial[(p * 2 + s) * E + i];
        vds[s * E + i] = sum;
    }
    __syncthreads();
    if (t < E) {
        float e1 = vds[t], e2 = vds[E + t];
        vds[2 * E + t] = e1 * e2;
        vds[3 * E + t] = fabsf(e1 - e2);
    }
    __syncthreads();
    int wave = t >> 6, lane = t & 63;
    int h = blockIdx.x * 8 + wave;
    if (h < 300) {
        const float4* w4 = (const float4*)(W_h + (size_t)h * 4 * E);
        const float4* v4 = (const float4*)vds;
        float4 w = w4[lane], v = v4[lane];
        float acc = w.x * v.x + w.y * v.y + w.z * v.z + w.w * v.w;
        if (lane < 36) {
            float4 w2 = w4[lane + 64], v2 = v4[lane + 64];
            acc += w2.x * v2.x + w2.y * v2.y + w2.z * v2.z + w2.w * v2.w;
        }
        #pragma unroll
        for (int off = 32; off > 0; off >>= 1) acc += __shfl_down(acc, off);
        if (lane == 0) hbuf[h] = 1.f / (1.f + expf(-(acc + b_h[h])));
    }
}

// Output layer + log_softmax. 512 threads (>=300 so hs fully covered).
__global__ __launch_bounds__(512) void out_kernel(const float* __restrict__ hbuf,
                                                  const float* __restrict__ W_o,
                                                  const float* __restrict__ b_o,
                                                  float* __restrict__ out) {
    __shared__ float hs[300];
    __shared__ float o[3];
    int t = threadIdx.x;
    if (t < 300) hs[t] = hbuf[t];
    __syncthreads();
    int wave = t >> 6, lane = t & 63;
    if (wave < 3) {
        float acc = 0.f;
        #pragma unroll
        for (int j = 0; j < 5; j++) {
            int h = lane + j * 64;
            if (h < 300) acc += W_o[wave * 300 + h] * hs[h];
        }
        #pragma unroll
        for (int off = 32; off > 0; off >>= 1) acc += __shfl_down(acc, off);
        if (lane == 0) o[wave] = acc + b_o[wave];
    }
    __syncthreads();
    if (t == 0) {
        float m = fmaxf(o[0], fmaxf(o[1], o[2]));
        float l = logf(expf(o[0] - m) + expf(o[1] - m) + expf(o[2] - m)) + m;
        out[0] = o[0] - l;
        out[1] = o[1] - l;
        out[2] = o[2] - l;
    }
}

extern "C" void kernel_launch(void* const* d_in, const int* in_sizes, int n_in,
                              void* d_out, int out_size, void* d_ws, size_t ws_size,
                              hipStream_t stream) {
    const int* words1 = (const int*)d_in[0];
    const int* vs1    = (const int*)d_in[1];
    const int* vo1    = (const int*)d_in[2];
    const int* vt1    = (const int*)d_in[3];
    const int* words2 = (const int*)d_in[4];
    const int* vs2    = (const int*)d_in[5];
    const int* vo2    = (const int*)d_in[6];
    const int* vt2    = (const int*)d_in[7];
    const float* noun_emb = (const float*)d_in[8];
    const float* subj     = (const float*)d_in[9];
    const float* obj      = (const float*)d_in[10];
    const float* W_h      = (const float*)d_in[11];
    const float* b_h      = (const float*)d_in[12];
    const float* W_o      = (const float*)d_in[13];
    const float* b_o      = (const float*)d_in[14];
    float* out = (float*)d_out;

    int*   count   = (int*)d_ws;                      // 20,000 ints
    int*   bucket  = count + 4 * NV;                  // 320,000 ints
    float* A       = (float*)(bucket + 4 * NV * CAP); // 2,000,000 floats
    float* partial = A + 4 * NV * E;                  // 12,800 floats
    float* hbuf    = partial + NPART * 2 * E;         // 300 floats

    init_kernel<<<(4 * NV + 255) / 256, 256, 0, stream>>>(count, partial);
    bucket_build_kernel<<<(40000 + 255) / 256, 256, 0, stream>>>(
        vs1, vo1, vt1, vs2, vo2, vt2, count, bucket);
    build_A_kernel<<<(4 * NV * 25 + 255) / 256, 256, 0, stream>>>(count, bucket, noun_emb, A);
    word_sum_kernel<<<250, 512, 0, stream>>>(words1, words2, noun_emb, partial);
    verb_panel_kernel<<<2 * NV, 512, 0, stream>>>(subj, obj, A, partial);
    hidden_kernel<<<38, 512, 0, stream>>>(partial, W_h, b_h, hbuf);
    out_kernel<<<1, 512, 0, stream>>>(hbuf, W_o, b_o, out);
}